// Round 10
// baseline (1020.470 us; speedup 1.0000x reference)
//
#include <hip/hip_runtime.h>

typedef short short8 __attribute__((ext_vector_type(8)));
typedef float f32x4 __attribute__((ext_vector_type(4)));
typedef unsigned u32x2 __attribute__((ext_vector_type(2)));
typedef unsigned u32x4 __attribute__((ext_vector_type(4)));

#define DD 4096
#define NLAYER 15
#define GB 64          // gemm blocks per layer kernel
#define NSLAB 512      // 8-row W slabs per layer
#define KITS 128       // 32-k tiles

__device__ __forceinline__ unsigned short f2bf(float f) {
  unsigned u = __float_as_uint(f);
  u += 0x7FFFu + ((u >> 16) & 1u);
  return (unsigned short)(u >> 16);
}
__device__ __forceinline__ unsigned pack2(float a, float b) {  // verified R8/R9
  unsigned ua = __float_as_uint(a) + 0x8000u;
  unsigned ub = __float_as_uint(b) + 0x8000u;
  return (ua >> 16) | (ub & 0xFFFF0000u);
}

// ---- W converter: fp32 row-major -> bf16 MFMA-fragment-blocked ----
// Wb elem layout: [kit 128][nfg 256][lane 64][e 8]  (lane = p*16+l15 -> col nfg*16+l15,
// k = kit*32 + p*8 + e).  Slab j = 8 rows [8j,8j+8) -> (kit=j>>2, p3=j&3) for ALL n.
__device__ __forceinline__ void wconv_slab(const float* __restrict__ Wsrc,
                                           unsigned short* __restrict__ Wb,
                                           int j, int tid, unsigned short* lds) {
  const float* src = Wsrc + (size_t)j * 8 * DD;
#pragma unroll
  for (int i = 0; i < 16; ++i) {                 // 128KB fp32 sequential read
    const int flat = (tid + 512 * i) * 4;
    f32x4 v = *(const f32x4*)(src + flat);
    u32x2 w2 = {pack2(v[0], v[1]), pack2(v[2], v[3])};
    *(u32x2*)(lds + flat) = w2;                  // lds bf16, same flat order [8][4096]
  }
  __syncthreads();
  const int kit = j >> 2, p3 = j & 3;
  unsigned short* dst = Wb + (size_t)kit * 131072 + p3 * 128;
#pragma unroll
  for (int i2 = 0; i2 < 8; ++i2) {
    const int wid = tid + 512 * i2;              // = global col n, 0..4095
    const int nfg = wid >> 4, lw = wid & 15;
    short8 s;
#pragma unroll
    for (int rr = 0; rr < 8; ++rr) s[rr] = (short)lds[rr * 4096 + wid];
    *(short8*)(dst + (size_t)nfg * 512 + lw * 8) = s;   // 16B store
  }
  __syncthreads();
}

// ---- k_pre: x -> A-blocked bf16  AND  W[0] -> Wb0 ----
__global__ __launch_bounds__(512) void k_pre(const float* __restrict__ x,
                                             unsigned short* __restrict__ h,
                                             const float* __restrict__ W0,
                                             unsigned short* __restrict__ Wb0) {
  __shared__ unsigned short lds[8 * 4096];
  const int bid = blockIdx.x, tid = threadIdx.x;
  if (bid < 128) {                               // tobf16: blocked [k>>5][m 256][k&31]
#pragma unroll
    for (int g = 0; g < 2; ++g) {
      const int flat = ((bid * 512 + tid) * 2 + g) * 8;
      const int m = flat >> 12, n = flat & (DD - 1);
      f32x4 a = *(const f32x4*)(x + flat);
      f32x4 b = *(const f32x4*)(x + flat + 4);
      short8 v;
#pragma unroll
      for (int q = 0; q < 4; ++q) { v[q] = (short)f2bf(a[q]); v[4 + q] = (short)f2bf(b[q]); }
      *(short8*)(h + (size_t)(n >> 5) * 8192 + m * 32 + (n & 31)) = v;
    }
  } else {
    const int wcid = bid - 128;                  // 0..383
    wconv_slab(W0, Wb0, wcid, tid, lds);
    if (wcid < 128) wconv_slab(W0, Wb0, wcid + 384, tid, lds);
  }
}

// ---- layer kernel: 64 GEMM blocks (full-K, no LDS, no barriers) + 448 WC blocks ----
__global__ __launch_bounds__(512) void k_layer(const unsigned short* __restrict__ A,
                                               const unsigned short* __restrict__ Wb,
                                               const float* __restrict__ bias,
                                               unsigned short* __restrict__ hout,
                                               float* __restrict__ fout,
                                               const float* __restrict__ wnext,
                                               unsigned short* __restrict__ Wbnext) {
  __shared__ unsigned short lds[8 * 4096];
  const int bid = blockIdx.x, tid = threadIdx.x;

  if (bid >= GB) {                               // converter for next layer
    if (!wnext) return;
    const int wcid = bid - GB;                   // 0..447
    wconv_slab(wnext, Wbnext, wcid, tid, lds);
    if (wcid < NSLAB - 448) wconv_slab(wnext, Wbnext, wcid + 448, tid, lds);
    return;
  }

  // ---- GEMM block: [256 m x 64 n], full K=4096; wave w owns m [w*32,+32), all 4 nf
  const int lane = tid & 63, w = tid >> 6;
  const int l15 = lane & 15, p = lane >> 4;
  const size_t arow = (size_t)(w * 32 + l15) * 32 + p * 8;       // + mf*512, + kb*8192
  const size_t bcol = (size_t)bid * 2048 + lane * 8;             // + nf*512, + kit*131072

  const f32x4 fz = {0.f, 0.f, 0.f, 0.f};
  f32x4 acc[2][4];
#pragma unroll
  for (int i = 0; i < 2; ++i)
#pragma unroll
    for (int q = 0; q < 4; ++q) acc[i][q] = fz;

  short8 ar[4][2], br[4][4];                     // depth-4 prefetch pipeline

#define LOADG(T, S)                                                         \
  do {                                                                      \
    _Pragma("unroll")                                                       \
    for (int mf = 0; mf < 2; ++mf)                                          \
      ar[S][mf] = *(const short8*)(A + (size_t)(T) * 8192 + arow + mf * 512); \
    _Pragma("unroll")                                                       \
    for (int nf = 0; nf < 4; ++nf)                                          \
      br[S][nf] = *(const short8*)(Wb + (size_t)(T) * 131072 + bcol + nf * 512); \
  } while (0)

  LOADG(0, 0); LOADG(1, 1); LOADG(2, 2); LOADG(3, 3);

  for (int tt = 0; tt < KITS; tt += 4) {
#define STEP(S)                                                             \
    do {                                                                    \
      const int t_ = tt + (S);                                              \
      _Pragma("unroll")                                                     \
      for (int nf = 0; nf < 4; ++nf)                                        \
        _Pragma("unroll")                                                   \
        for (int mf = 0; mf < 2; ++mf)                                      \
          acc[mf][nf] = __builtin_amdgcn_mfma_f32_16x16x32_bf16(            \
              ar[S][mf], br[S][nf], acc[mf][nf], 0, 0, 0);                  \
      if (t_ + 4 < KITS) LOADG(t_ + 4, S);                                  \
    } while (0)
    STEP(0); STEP(1); STEP(2); STEP(3);
#undef STEP
  }
#undef LOADG

  // fused epilogue: bias + relu -> blocked bf16 h (or fp32 out on last layer)
  const int n0 = bid * 64;
#pragma unroll
  for (int mf = 0; mf < 2; ++mf)
#pragma unroll
    for (int nf = 0; nf < 4; ++nf) {
      const float bv = bias[n0 + nf * 16 + l15];
      f32x4 a = acc[mf][nf], o;
#pragma unroll
      for (int q = 0; q < 4; ++q) a[q] = fmaxf(a[q] + bv, 0.f);
      if (fout) {
#pragma unroll
        for (int q = 0; q < 4; ++q)
          fout[(size_t)(w * 32 + mf * 16 + 4 * p + q) * DD + n0 + nf * 16 + l15] = a[q];
      } else {
#pragma unroll
        for (int q = 0; q < 4; ++q) o[q] = __shfl_xor(a[q], 1);
        if ((l15 & 1) == 0) {
          const int kb = bid * 2 + (nf >> 1);
          const int nc = (nf & 1) * 16 + l15;
#pragma unroll
          for (int q = 0; q < 4; ++q) {
            unsigned pk = (unsigned)f2bf(a[q]) | ((unsigned)f2bf(o[q]) << 16);
            *(unsigned*)(hout + (size_t)kb * 8192 +
                         (w * 32 + mf * 16 + 4 * p + q) * 32 + nc) = pk;
          }
        }
      }
    }
}

extern "C" void kernel_launch(void* const* d_in, const int* in_sizes, int n_in,
                              void* d_out, int out_size, void* d_ws, size_t ws_size,
                              hipStream_t stream) {
  const float* x = (const float*)d_in[0];
  const float* W = (const float*)d_in[1];
  const float* b = (const float*)d_in[2];
  float* out = (float*)d_out;

  char* ws = (char*)d_ws;
  unsigned short* h0  = (unsigned short*)ws;                  // 2 MB A-blocked bf16
  unsigned short* h1  = (unsigned short*)(ws + (1 << 21));    // 2 MB
  unsigned short* Wb0 = (unsigned short*)(ws + (1 << 22));    // 32 MB frag-blocked
  unsigned short* Wb1 = (unsigned short*)(ws + (1 << 22) + (32u << 20));

  k_pre<<<512, 512, 0, stream>>>(x, h0, W, Wb0);

  unsigned short* hc = h0;
  unsigned short* hn = h1;
  for (int l = 0; l < NLAYER; ++l) {
    const bool last = (l == NLAYER - 1);
    unsigned short* wbc = (l & 1) ? Wb1 : Wb0;
    unsigned short* wbn = (l & 1) ? Wb0 : Wb1;
    k_layer<<<512, 512, 0, stream>>>(hc, wbc, b + (size_t)l * DD, hn,
                                     last ? out : nullptr,
                                     last ? nullptr : (W + (size_t)(l + 1) * DD * DD),
                                     wbn);
    unsigned short* t = hc; hc = hn; hn = t;
  }
}

// Round 11
// 541.248 us; speedup vs baseline: 1.8854x; 1.8854x over previous
//
#include <hip/hip_runtime.h>

typedef short short8 __attribute__((ext_vector_type(8)));
typedef float f32x4 __attribute__((ext_vector_type(4)));
typedef unsigned u32x4 __attribute__((ext_vector_type(4)));

#define DD 4096
#define KSL 16        // split-K factor
#define KSLAB 256     // DD/KSL k-rows per block
#define NT 8          // k-tiles of 32 per block
#define NLAYER 15

__device__ __forceinline__ unsigned short f2bf(float f) {
  unsigned u = __float_as_uint(f);
  u += 0x7FFFu + ((u >> 16) & 1u);   // round-to-nearest-even
  return (unsigned short)(u >> 16);
}
__device__ __forceinline__ float bf2f(unsigned short b) {
  return __uint_as_float(((unsigned)b) << 16);
}

// fp32 x [256][4096] -> bf16 h blocked [k>>5][m 256][k&31]
__global__ __launch_bounds__(256) void k_tobf16(const float* __restrict__ x,
                                                unsigned short* __restrict__ h) {
  const size_t e = ((size_t)blockIdx.x * 256 + threadIdx.x) * 8;
  const int m = (int)(e >> 12), n = (int)(e & (DD - 1));
  f32x4 a = *(const f32x4*)(x + e);
  f32x4 b = *(const f32x4*)(x + e + 4);
  short8 v;
#pragma unroll
  for (int j = 0; j < 4; ++j) { v[j] = (short)f2bf(a[j]); v[4 + j] = (short)f2bf(b[j]); }
  *(short8*)(h + (size_t)(n >> 5) * 8192 + m * 32 + (n & 31)) = v;
}

// 4x4 quad transpose across p-lane groups (verified R3-R6)
__device__ __forceinline__ void qtrans(f32x4 v, int p, unsigned& lo, unsigned& hi) {
  unsigned d0 = (unsigned)f2bf(v[0]) | ((unsigned)f2bf(v[1]) << 16);
  unsigned d1 = (unsigned)f2bf(v[2]) | ((unsigned)f2bf(v[3]) << 16);
  unsigned o0 = (unsigned)__shfl_xor((int)d0, 16);
  unsigned o1 = (unsigned)__shfl_xor((int)d1, 16);
  unsigned r0, r1;
  if ((p & 1) == 0) { r0 = (d0 & 0xFFFFu) | (o0 << 16); r1 = (d0 >> 16) | (o0 & 0xFFFF0000u); }
  else              { r0 = (o1 & 0xFFFFu) | (d1 << 16); r1 = (o1 >> 16) | (d1 & 0xFFFF0000u); }
  unsigned q0 = (unsigned)__shfl_xor((int)r0, 32);
  unsigned q1 = (unsigned)__shfl_xor((int)r1, 32);
  if (p < 2) { lo = r0; hi = q0; } else { lo = q1; hi = r1; }
}

// Split-K GEMM partial (R6 structure, 509us verified) with ONE change: bid mapping
// flipped so ADJACENT co-dispatched blocks read ADJACENT 1KB chunks of the SAME
// W k-rows -> aggregate 16KB-contiguous DRAM request stream per k-row group.
__global__ __launch_bounds__(512, 2) void k_gemm(const unsigned short* __restrict__ A,
                                                 const float* __restrict__ W,
                                                 unsigned short* __restrict__ part) {
  __shared__ __align__(16) unsigned char smem[32768];  // 2 x 16KB W-frag buffers
  const int bid  = blockIdx.x;
  const int nblk = bid & 15;        // R11 flip: adjacent bids = adjacent n-chunks
  const int ks   = bid >> 4;        // same-ks cohort spread across XCDs; A via IF$
  const int n0   = nblk * 256;
  const int tid  = threadIdx.x;
  const int lane = tid & 63;
  const int wave = tid >> 6;        // 0..7
  const int l15  = lane & 15;
  const int p    = lane >> 4;       // 0..3
  const int pp   = ((p & 1) << 1) | (p >> 1);
  const int nw   = 4 * l15 + pp;    // transposed n-col within 64-strip

  const int kg0 = wave & 3, ns0 = wave >> 2;
  const int kg1 = kg0,      ns1 = ns0 + 2;
  const float* w0 = W + (size_t)(ks * KSLAB + 8 * kg0 + p) * DD + n0 + ns0 * 64 + 4 * l15;
  const float* w1 = W + (size_t)(ks * KSLAB + 8 * kg1 + p) * DD + n0 + ns1 * 64 + 4 * l15;

  const int wm = wave & 3, wn = wave >> 2;          // wave tile [64 m x 128 n]
  const size_t arow = (size_t)(wm * 64 + l15) * 32 + 8 * p;
  const unsigned short* Ab = A + (size_t)ks * 8 * 8192 + arow;

  const f32x4 fz = {0.f, 0.f, 0.f, 0.f};
  f32x4 acc[4][8];
#pragma unroll
  for (int i = 0; i < 4; ++i)
#pragma unroll
    for (int j = 0; j < 8; ++j) acc[i][j] = fz;

  f32x4 wr[2][4];
  short8 ar[2][4];

#define LOADW(T, S)                                                   \
  do {                                                                \
    const float* s0_ = w0 + (size_t)(T) * 32 * DD;                    \
    const float* s1_ = w1 + (size_t)(T) * 32 * DD;                    \
    wr[S][0] = *(const f32x4*)s0_;                                    \
    wr[S][1] = *(const f32x4*)(s0_ + 4 * DD);                         \
    wr[S][2] = *(const f32x4*)s1_;                                    \
    wr[S][3] = *(const f32x4*)(s1_ + 4 * DD);                         \
  } while (0)

#define LOADA(T, S)                                                   \
  do {                                                                \
    _Pragma("unroll")                                                 \
    for (int mf = 0; mf < 4; ++mf)                                    \
      ar[S][mf] = *(const short8*)(Ab + (size_t)(T) * 8192 + mf * 16 * 32); \
  } while (0)

#define STAGE(S, BUF)                                                 \
  do {                                                                \
    unsigned la, ha, lb, hb;                                          \
    qtrans(wr[S][0], p, la, ha);                                      \
    qtrans(wr[S][1], p, lb, hb);                                      \
    u32x4 v0 = {la, ha, lb, hb};                                      \
    *(u32x4*)(smem + (BUF) * 16384 + kg0 * 4096 + (ns0 * 64 + nw) * 16) = v0; \
    qtrans(wr[S][2], p, la, ha);                                      \
    qtrans(wr[S][3], p, lb, hb);                                      \
    u32x4 v1 = {la, ha, lb, hb};                                      \
    *(u32x4*)(smem + (BUF) * 16384 + kg1 * 4096 + (ns1 * 64 + nw) * 16) = v1; \
  } while (0)

  // prologue
  LOADW(0, 0);
  LOADW(1, 1);
  LOADA(0, 0);
  STAGE(0, 0);
  __syncthreads();

#pragma unroll
  for (int it = 0; it < NT; ++it) {
    if (it + 1 < NT) LOADA(it + 1, (it + 1) & 1);
    if (it + 1 < NT) STAGE((it + 1) & 1, (it + 1) & 1);
    if (it + 2 < NT) LOADW(it + 2, it & 1);
    const unsigned char* bbase = smem + (it & 1) * 16384 + p * 4096 + (wn * 128 + l15) * 16;
#pragma unroll
    for (int nf = 0; nf < 8; ++nf) {
      short8 bf = *(const short8*)(bbase + nf * 256);
#pragma unroll
      for (int mf = 0; mf < 4; ++mf)
        acc[mf][nf] = __builtin_amdgcn_mfma_f32_16x16x32_bf16(ar[it & 1][mf], bf,
                                                              acc[mf][nf], 0, 0, 0);
    }
    __syncthreads();
  }
#undef LOADW
#undef LOADA
#undef STAGE

  // bf16 partial write: pair adjacent cols via lane shuffle, even lanes store u32
  unsigned short* pl = part + (size_t)ks * (256 * 4096);
#pragma unroll
  for (int mf = 0; mf < 4; ++mf)
#pragma unroll
    for (int nf = 0; nf < 8; ++nf) {
      f32x4 a = acc[mf][nf], o;
#pragma unroll
      for (int j = 0; j < 4; ++j) o[j] = __shfl_xor(a[j], 1);
      if ((l15 & 1) == 0) {
        const int col = n0 + wn * 128 + nf * 16 + l15;
        const int rb  = wm * 64 + mf * 16 + 4 * p;
#pragma unroll
        for (int j = 0; j < 4; ++j) {
          unsigned pk = (unsigned)f2bf(a[j]) | ((unsigned)f2bf(o[j]) << 16);
          *(unsigned*)((char*)pl + ((size_t)(rb + j) * 4096 + col) * 2) = pk;
        }
      }
    }
}

// sum 16 bf16 partials + bias, relu -> bf16 blocked h (+ fp32 out on last layer)
__global__ __launch_bounds__(256) void k_reduce(const unsigned short* __restrict__ part,
                                                const float* __restrict__ bias,
                                                unsigned short* __restrict__ hout,
                                                float* __restrict__ fout) {
  const size_t e = ((size_t)blockIdx.x * 256 + threadIdx.x) * 8;
  float s[8] = {0.f, 0.f, 0.f, 0.f, 0.f, 0.f, 0.f, 0.f};
#pragma unroll
  for (int ks = 0; ks < KSL; ++ks) {
    short8 v = *(const short8*)(part + (size_t)ks * (256 * 4096) + e);
#pragma unroll
    for (int j = 0; j < 8; ++j) s[j] += bf2f((unsigned short)v[j]);
  }
  const int m = (int)(e >> 12), n = (int)(e & (DD - 1));
#pragma unroll
  for (int j = 0; j < 8; ++j) s[j] = fmaxf(s[j] + bias[n + j], 0.f);
  short8 o;
#pragma unroll
  for (int j = 0; j < 8; ++j) o[j] = (short)f2bf(s[j]);
  *(short8*)(hout + (size_t)(n >> 5) * 8192 + m * 32 + (n & 31)) = o;
  if (fout) {
    f32x4 o0, o1;
#pragma unroll
    for (int j = 0; j < 4; ++j) { o0[j] = s[j]; o1[j] = s[4 + j]; }
    float* dst = fout + e;
    *(f32x4*)dst = o0;
    *(f32x4*)(dst + 4) = o1;
  }
}

extern "C" void kernel_launch(void* const* d_in, const int* in_sizes, int n_in,
                              void* d_out, int out_size, void* d_ws, size_t ws_size,
                              hipStream_t stream) {
  const float* x = (const float*)d_in[0];
  const float* W = (const float*)d_in[1];
  const float* b = (const float*)d_in[2];
  float* out = (float*)d_out;

  char* ws = (char*)d_ws;
  unsigned short* h0 = (unsigned short*)ws;                 // 2 MB bf16 blocked
  unsigned short* h1 = (unsigned short*)(ws + (1 << 21));   // 2 MB
  unsigned short* part = (unsigned short*)(ws + (1 << 22)); // 16 x 2 MB bf16 partials

  k_tobf16<<<512, 256, 0, stream>>>(x, h0);
  unsigned short* hc = h0;
  unsigned short* hn = h1;
  for (int l = 0; l < NLAYER; ++l) {
    const bool last = (l == NLAYER - 1);
    k_gemm<<<256, 512, 0, stream>>>(hc, W + (size_t)l * DD * DD, part);
    k_reduce<<<512, 256, 0, stream>>>(part, b + (size_t)l * DD, hn,
                                      last ? out : nullptr);
    unsigned short* t = hc; hc = hn; hn = t;
  }
}